// Round 1
// baseline (215.843 us; speedup 1.0000x reference)
//
#include <hip/hip_runtime.h>
#include <hip/hip_bf16.h>

// Identity-select copy: out = ((x >= 1001) || (x <= 447113)) ? x : 0
// Tautologically true for all non-NaN x -> effectively a copy.
// Memory-bound: 512 MiB in + 512 MiB out. Target ~6.3 TB/s.

#define MAX_ITEMS 447113.0f
#define MIN_ITEMS 1001.0f

__global__ void exilu_copy_kernel(const float4* __restrict__ in,
                                  float4* __restrict__ out,
                                  long long n4) {
    long long stride = (long long)gridDim.x * blockDim.x;
    for (long long i = (long long)blockIdx.x * blockDim.x + threadIdx.x;
         i < n4; i += stride) {
        float4 v = in[i];
        float4 r;
        r.x = ((v.x >= MIN_ITEMS) || (v.x <= MAX_ITEMS)) ? v.x : 0.0f;
        r.y = ((v.y >= MIN_ITEMS) || (v.y <= MAX_ITEMS)) ? v.y : 0.0f;
        r.z = ((v.z >= MIN_ITEMS) || (v.z <= MAX_ITEMS)) ? v.z : 0.0f;
        r.w = ((v.w >= MIN_ITEMS) || (v.w <= MAX_ITEMS)) ? v.w : 0.0f;
        out[i] = r;
    }
}

extern "C" void kernel_launch(void* const* d_in, const int* in_sizes, int n_in,
                              void* d_out, int out_size, void* d_ws, size_t ws_size,
                              hipStream_t stream) {
    const float* in = (const float*)d_in[0];
    float* out = (float*)d_out;
    long long n = (long long)in_sizes[0];   // 4096*32768 = 134217728, divisible by 4
    long long n4 = n / 4;

    const int block = 256;
    int grid = 2048;  // 256 CUs * 8 blocks/CU; grid-stride covers the rest
    long long needed = (n4 + block - 1) / block;
    if (needed < grid) grid = (int)needed;

    exilu_copy_kernel<<<grid, block, 0, stream>>>(
        (const float4*)in, (float4*)out, n4);
}

// Round 3
// 180.012 us; speedup vs baseline: 1.1990x; 1.1990x over previous
//
#include <hip/hip_runtime.h>
#include <hip/hip_bf16.h>

// Identity-select copy: out = ((x >= 1001) || (x <= 447113)) ? x : 0
// Tautologically true for all non-NaN x -> effectively a copy.
// Memory-bound: 512 MiB in + 512 MiB out. Target ~6.3 TB/s (m13 float4-copy ceiling).
//
// Each thread copies 4x 16B at block-coalesced offsets, no grid-stride loop,
// nontemporal load/store (zero reuse). Uses clang ext_vector_type (native
// vector) because __builtin_nontemporal_* rejects HIP_vector_type structs.

#define MAX_ITEMS 447113.0f
#define MIN_ITEMS 1001.0f

typedef float v4f __attribute__((ext_vector_type(4)));

__device__ __forceinline__ v4f sel4(v4f v) {
    v4f r;
    r.x = ((v.x >= MIN_ITEMS) || (v.x <= MAX_ITEMS)) ? v.x : 0.0f;
    r.y = ((v.y >= MIN_ITEMS) || (v.y <= MAX_ITEMS)) ? v.y : 0.0f;
    r.z = ((v.z >= MIN_ITEMS) || (v.z <= MAX_ITEMS)) ? v.z : 0.0f;
    r.w = ((v.w >= MIN_ITEMS) || (v.w <= MAX_ITEMS)) ? v.w : 0.0f;
    return r;
}

__global__ void __launch_bounds__(256) exilu_copy_kernel(
        const v4f* __restrict__ in, v4f* __restrict__ out, long long n4) {
    // Each block covers blockDim.x * 4 consecutive float4s.
    long long blockBase = (long long)blockIdx.x * (blockDim.x * 4);
    long long i0 = blockBase + threadIdx.x;
    long long s  = blockDim.x;

    long long i1 = i0 + s, i2 = i0 + 2 * s, i3 = i0 + 3 * s;

    bool b0 = i0 < n4, b1 = i1 < n4, b2 = i2 < n4, b3 = i3 < n4;

    // Issue all 4 loads before any store (MLP).
    v4f v0 = {}, v1 = {}, v2 = {}, v3 = {};
    if (b0) v0 = __builtin_nontemporal_load(&in[i0]);
    if (b1) v1 = __builtin_nontemporal_load(&in[i1]);
    if (b2) v2 = __builtin_nontemporal_load(&in[i2]);
    if (b3) v3 = __builtin_nontemporal_load(&in[i3]);

    if (b0) __builtin_nontemporal_store(sel4(v0), &out[i0]);
    if (b1) __builtin_nontemporal_store(sel4(v1), &out[i1]);
    if (b2) __builtin_nontemporal_store(sel4(v2), &out[i2]);
    if (b3) __builtin_nontemporal_store(sel4(v3), &out[i3]);
}

extern "C" void kernel_launch(void* const* d_in, const int* in_sizes, int n_in,
                              void* d_out, int out_size, void* d_ws, size_t ws_size,
                              hipStream_t stream) {
    const float* in = (const float*)d_in[0];
    float* out = (float*)d_out;
    long long n = (long long)in_sizes[0];   // 4096*32768 = 134217728
    long long n4 = n / 4;                   // 33554432 float4s

    const int block = 256;
    const long long perBlock = (long long)block * 4;   // 1024 float4s / block
    int grid = (int)((n4 + perBlock - 1) / perBlock);  // 32768 blocks, exact

    exilu_copy_kernel<<<grid, block, 0, stream>>>(
        (const v4f*)in, (v4f*)out, n4);
}